// Round 11
// baseline (1281.838 us; speedup 1.0000x reference)
//
#include <hip/hip_runtime.h>
#include <hip/hip_bf16.h>

// LSTM2: B=1024, T=1024, H=64. R27: R26 (2 co-resident blocks/CU) + fix
// for a LATENT TAIL RACE present since R23: Q writes headp[u&3] AFTER
// publishing qf=u+1 (by design -- keeps it off the critical chain). All
// in-loop reads are lag-2 and ordered by a LATER publish, but the FINAL
// headp(Tt-1) write has no later publish -- the tail poll qf>=Tt does not
// order it. R23/R25 won this race by luck (headp write ~10 insts after
// publish); R26's 2-blocks/CU jitter lost it -> stale out(:,Tt-1), absmax
// 2.2e-2 (same signature as R19). Fix: flg2[4] "tail done" flags -- each
// Q wave's lane 0 publishes flg2[gw]=1 AFTER its final headp write; w4's
// tail polls all four flg2 (implies qf=Tt) before reading headp(Tt-2/1).
// Steady-state loop is untouched, so this round cleanly measures the R26
// occupancy theory: R23 has 8 waves/CU (23% occ) and every chain stall is
// a wasted issue slot; two independent blocks/CU interleave at the SIMD
// scheduler level (R24 lesson: intra-wave interleave across a blocking
// spin is impossible; TLP must come from other waves/blocks).
// Config: NBat=2, grid 512, __launch_bounds__(512,4) -> 2 blocks/CU
// (VGPR 76 < 128 cap; LDS 18.5KB x2 << 160KB). Lane geometry (R24-
// verified GB=2): bsel=m&1, q2=(m>>1)&3, dup=m&8 (compute, don't store),
// s1=m&2, s2=m&4, head xor {2,4,16,32}, lanes 0-1 store headp.
// Protocol per block (audited R19/R20): h1ring 4-deep, P<=3 ahead;
// flg[0..3]=pf, flg[4..7]=qf; lane-0 publish after guarded ds_write
// (same-wave DS in-order). P(t): min(pf)>=t && min(qf)>=t-3.
// Q(u): min(pf)>=u+1 && min(qf)>=u. w4 finalizes out at LAG 2 from
// depth-4 headp. Retained: batch-replicated cols + register mux,
// pre-scaled activations, depth-1 P MFMAs, 2-deep Q chains, setprio,
// ai-init hoisted above poll, HSTR=80, LDS outbuf + coalesced flush.
// Layouts (m89/m91/m120): A[m=lane&15][k=(lane>>4)*8+j],
// B[k=(lane>>4)*8+j][n=lane&15], C/D: row=(lane>>4)*4+reg, col=lane&15.

typedef _Float16 f16x8 __attribute__((ext_vector_type(8)));
typedef float    f32x4 __attribute__((ext_vector_type(4)));

namespace {
constexpr int Bb = 1024;
constexpr int Tt = 1024;
constexpr int NBat = 2;    // batches per block (2 blocks/CU)
constexpr int HSTR = 80;   // f16 stride per batch row of h (bank-tuned)
constexpr int XSTR = 1025; // f32 stride per batch row of x

// Pre-scaled activations: gate rows of W/b folded with -log2e (i,f,o) and
// -2log2e (g) at load, so no input multiply here.
__device__ __forceinline__ float sigm_pre(float a) {   // a = -1.4427*x
    return __builtin_amdgcn_rcpf(1.0f + __builtin_amdgcn_exp2f(a));
}
__device__ __forceinline__ float tanh_pre(float a) {   // a = -2.8854*x
    return fmaf(2.0f, __builtin_amdgcn_rcpf(1.0f + __builtin_amdgcn_exp2f(a)), -1.0f);
}
__device__ __forceinline__ float tanh_f(float x) {     // unscaled input (c-path)
    float e = __builtin_amdgcn_exp2f(-2.8853900817779268f * x);
    return fmaf(2.0f, __builtin_amdgcn_rcpf(1.0f + e), -1.0f);
}
// Dtype sniff (proven R2-R26).
__device__ __forceinline__ bool detect_f32(const void* w) {
    const unsigned short* p = (const unsigned short*)w;
    int sane = 0;
    for (int i = 0; i < 64; ++i) {
        int e = (p[2 * i] >> 7) & 0xFF;
        if (e >= 107 && e <= 129) ++sane;
    }
    return sane < 32;
}
__device__ __forceinline__ float ld(const void* p, int i, bool f32) {
    return f32 ? ((const float*)p)[i]
               : __bfloat162float(((const __hip_bfloat16*)p)[i]);
}
__device__ __forceinline__ void st(void* p, int i, float v, bool f32) {
    if (f32) ((float*)p)[i] = v;
    else     ((__hip_bfloat16*)p)[i] = __float2bfloat16(v);
}
// Lane-parallel spin (R20/R23 version): lane i watches flg[i&7]; P-flags
// (idx<4) vs tp, Q-flags vs tq. ONE broadcast ds_read_b32 per spin.
__device__ __forceinline__ void poll_flags(const int* f, int tp, int tq, int lane) {
    const int idx = lane & 7;
    const int thr = (idx < 4) ? tp : tq;
    for (;;) {
        int v = ((const volatile int*)f)[idx];
        if (__all(v >= thr)) break;
    }
    __builtin_amdgcn_sched_barrier(0);
    asm volatile("" ::: "memory");
}
} // namespace

__global__ __launch_bounds__(512, 4) void lstm2_kernel(
    const void* __restrict__ x,      // [B, T]
    const void* __restrict__ w_ih1,  // [256, 1]
    const void* __restrict__ w_hh1,  // [256, 64]
    const void* __restrict__ b_ih1,  // [256]
    const void* __restrict__ b_hh1,  // [256]
    const void* __restrict__ w_ih2,  // [256, 64]
    const void* __restrict__ w_hh2,  // [256, 64]
    const void* __restrict__ b_ih2,  // [256]
    const void* __restrict__ b_hh2,  // [256]
    const void* __restrict__ w_lin,  // [1, 64]
    const void* __restrict__ b_lin,  // [1]
    void* __restrict__ out)          // [B, T]
{
    const int tid  = threadIdx.x;
    const int lane = tid & 63;
    const int w    = tid >> 6;       // wave 0..7
    const int gw   = w & 3;          // group-local wave -> unit group 16gw..
    const bool isP = w < 4;          // P: L1 recurrence; Q: L2 pipeline
    const int m    = lane & 15;      // MFMA col
    const int quad = lane >> 4;
    const int bb   = blockIdx.x * NBat;

    const bool f32 = detect_f32(w_hh1);

    __shared__ float                  xs[NBat * XSTR];
    __shared__ __align__(16) _Float16 h1ring[4][NBat * HSTR]; // 4-deep ring
    __shared__ __align__(16) _Float16 h2buf[2][NBat * HSTR];  // parity (Q)
    __shared__ __align__(16) float    headp[4][NBat][4];      // [u&3][b][gw]
    __shared__ float                  outbuf[NBat * Tt];      // staged outputs
    __shared__ int                    flg[8];                 // 0..3 pf, 4..7 qf
    __shared__ int                    flg2[4];                // tail-done per Q wave

    // ---- stage x + zero h buffers ----
    for (int i = tid; i < NBat * 1024; i += 512)
        xs[(i >> 10) * XSTR + (i & 1023)] = ld(x, (bb + (i >> 10)) * Tt + (i & 1023), f32);
    for (int i = tid; i < NBat * HSTR; i += 512) {
        h1ring[0][i] = (_Float16)0; h1ring[1][i] = (_Float16)0;
        h1ring[2][i] = (_Float16)0; h1ring[3][i] = (_Float16)0;
        h2buf[0][i] = (_Float16)0;  h2buf[1][i] = (_Float16)0;
    }
    if (tid < 8) flg[tid] = 0;
    if (tid < 4) flg2[tid] = 0;

    // ---- A-fragments, gate-interleaved rows (R13), activation-scale folded ----
    // tile row (lane&15) = 4*u_loc + g -> mem row 64*g + 16*gw + 4q + u_loc
    const int arow = lane & 15;
    const int g_ld = arow & 3;
    const int u_ld = arow >> 2;
    const float scA = (g_ld == 2) ? -2.8853900817779268f : -1.4426950408889634f;
    f16x8 wfA[4][2], wfB[4][2];   // P: wfA=W1 (wfB zero); Q: wfA=W2, wfB=W3
    {
        const void* MA = isP ? w_hh1 : w_ih2;
#pragma unroll
        for (int q = 0; q < 4; ++q) {
            const int row = 64 * g_ld + 16 * gw + 4 * q + u_ld;
#pragma unroll
            for (int s = 0; s < 2; ++s) {
                const int base = row * 64 + 32 * s + quad * 8;
                if (f32) {
                    const float* A = (const float*)MA;
                    const float* B = (const float*)w_hh2;
#pragma unroll
                    for (int j = 0; j < 8; ++j) {
                        wfA[q][s][j] = (_Float16)(scA * A[base + j]);
                        wfB[q][s][j] = isP ? (_Float16)0.0f
                                           : (_Float16)(scA * B[base + j]);
                    }
                } else {
                    const __hip_bfloat16* A = (const __hip_bfloat16*)MA;
                    const __hip_bfloat16* B = (const __hip_bfloat16*)w_hh2;
#pragma unroll
                    for (int j = 0; j < 8; ++j) {
                        wfA[q][s][j] = (_Float16)(scA * __bfloat162float(A[base + j]));
                        wfB[q][s][j] = isP ? (_Float16)0.0f
                                           : (_Float16)(scA * __bfloat162float(B[base + j]));
                    }
                }
            }
        }
    }
    // bias / wx per (tile q, gate r): D row r of tile q = gate r, unit 16gw+4q+quad
    f32x4 bv[4], wxv[4];
#pragma unroll
    for (int q = 0; q < 4; ++q)
#pragma unroll
        for (int r = 0; r < 4; ++r) {
            const int row = 64 * r + 16 * gw + 4 * q + quad;
            const float sg = (r == 2) ? -2.8853900817779268f : -1.4426950408889634f;
            bv[q][r] = sg * (isP ? (ld(b_ih1, row, f32) + ld(b_hh1, row, f32))
                                 : (ld(b_ih2, row, f32) + ld(b_hh2, row, f32)));
            wxv[q][r] = isP ? sg * ld(w_ih1, row, f32) : 0.0f;
        }
    // cell ownership (NBat=2, R24-verified geometry): lane (quad,m) owns
    // (batch m&1, unit 16gw + 4*((m>>1)&3) + quad); lanes m and m+8 dup.
    const int bsel = m & 1;
    const int q2   = (m >> 1) & 3;
    const bool dup = (m & 8) != 0;   // duplicate lane: compute, don't store
    const int hidx = bsel * HSTR + 16 * gw + 4 * q2 + quad;
    const bool s1 = (m & 2) != 0, s2 = (m & 4) != 0;
    const float wl_u = ld(w_lin, 16 * gw + 4 * q2 + quad, f32);
    const float blin = ld(b_lin, 0, f32);
    float cst = 0.0f;                 // c-state of the owned cell
    __syncthreads();   // xs + zeroed bufs + flags visible

    if (isP) {
        // ================= P: L1 recurrence, self-paced =================
#pragma unroll 4
        for (int t = 0; t < Tt; ++t) {
            // acc-init before poll: reads only static xs/regs
            const float xt = xs[bsel * XSTR + t];
            f32x4 ai[4];
#pragma unroll
            for (int q = 0; q < 4; ++q)
#pragma unroll
                for (int r = 0; r < 4; ++r)
                    ai[q][r] = fmaf(xt, wxv[q][r], bv[q][r]);
            poll_flags(flg, t, t - 3, lane);   // group sync + ring-not-full
            f32x4 acc[4];
            if (t > 0) {
                const _Float16* hp = h1ring[(t - 1) & 3] + bsel * HSTR;
                const f16x8 pa0 = *(const f16x8*)(hp + quad * 8);
                const f16x8 pa1 = *(const f16x8*)(hp + 32 + quad * 8);
                __builtin_amdgcn_s_setprio(1);
#pragma unroll
                for (int q = 0; q < 4; ++q) {   // depth-1: independent k-halves
                    f32x4 p0 = __builtin_amdgcn_mfma_f32_16x16x32_f16(wfA[q][0], pa0, ai[q], 0, 0, 0);
                    f32x4 p1 = __builtin_amdgcn_mfma_f32_16x16x32_f16(wfA[q][1], pa1, f32x4{0,0,0,0}, 0, 0, 0);
                    acc[q] = p0 + p1;
                }
                __builtin_amdgcn_s_setprio(0);
            } else {
#pragma unroll
                for (int q = 0; q < 4; ++q) acc[q] = ai[q];
            }
            // ---- register mux: g = acc[q2] (12 cndmasks, no LDS) ----
            f32x4 g;
#pragma unroll
            for (int r = 0; r < 4; ++r) {
                float lo = s1 ? acc[1][r] : acc[0][r];
                float hi = s1 ? acc[3][r] : acc[2][r];
                g[r] = s2 ? hi : lo;
            }
            // ---- cell (1 per lane; dup lanes compute, don't store) ----
            float ig = sigm_pre(g[0]), fg = sigm_pre(g[1]);
            float gg = tanh_pre(g[2]), og = sigm_pre(g[3]);
            cst = fmaf(fg, cst, ig * gg);
            float h = og * tanh_f(cst);
            if (!dup) h1ring[t & 3][hidx] = (_Float16)h;
            if (lane == 0) {          // publish: DS in-order, no waitcnt
                asm volatile("" ::: "memory");
                *(volatile int*)&flg[gw] = t + 1;
            }
        }
    } else {
        // ================= Q: L2 pipeline, self-paced =================
#pragma unroll 4
        for (int u = 0; u < Tt; ++u) {
            poll_flags(flg, u + 1, u, lane);   // h1(u) ready + own group done u-1
            // ---- finalize out(u-2) -> LDS outbuf (lag 2, off-chain) ----
            if (u > 1 && w == 4 && lane < NBat) {
                f32x4 v = *(const f32x4*)&headp[(u - 2) & 3][lane][0];
                outbuf[lane * Tt + (u - 2)] = blin + (v[0] + v[1]) + (v[2] + v[3]);
            }
            // ---- a2(u) = W2.h1(u) + W3.h2(u-1) + b2 (pre-scaled) ----
            const _Float16* h1p = h1ring[u & 3] + bsel * HSTR;
            const _Float16* h2p = h2buf[(u + 1) & 1] + bsel * HSTR;  // (u-1) parity
            const f16x8 pa0 = *(const f16x8*)(h1p + quad * 8);
            const f16x8 pa1 = *(const f16x8*)(h1p + 32 + quad * 8);
            const f16x8 pb0 = *(const f16x8*)(h2p + quad * 8);
            const f16x8 pb1 = *(const f16x8*)(h2p + 32 + quad * 8);
            f32x4 acc[4];
            __builtin_amdgcn_s_setprio(1);
#pragma unroll
            for (int q = 0; q < 4; ++q) {   // two independent 2-deep chains
                f32x4 p2 = __builtin_amdgcn_mfma_f32_16x16x32_f16(wfA[q][0], pa0, bv[q], 0, 0, 0);
                p2 = __builtin_amdgcn_mfma_f32_16x16x32_f16(wfA[q][1], pa1, p2, 0, 0, 0);
                f32x4 p3 = __builtin_amdgcn_mfma_f32_16x16x32_f16(wfB[q][0], pb0, f32x4{0,0,0,0}, 0, 0, 0);
                p3 = __builtin_amdgcn_mfma_f32_16x16x32_f16(wfB[q][1], pb1, p3, 0, 0, 0);
                acc[q] = p2 + p3;
            }
            __builtin_amdgcn_s_setprio(0);
            // ---- register mux + cell ----
            f32x4 g;
#pragma unroll
            for (int r = 0; r < 4; ++r) {
                float lo = s1 ? acc[1][r] : acc[0][r];
                float hi = s1 ? acc[3][r] : acc[2][r];
                g[r] = s2 ? hi : lo;
            }
            float ig = sigm_pre(g[0]), fg = sigm_pre(g[1]);
            float gg = tanh_pre(g[2]), og = sigm_pre(g[3]);
            cst = fmaf(fg, cst, ig * gg);
            float h = og * tanh_f(cst);
            if (!dup) h2buf[u & 1][hidx] = (_Float16)h;
            if (lane == 0) {          // publish right after h2 write
                asm volatile("" ::: "memory");
                *(volatile int*)&flg[4 + gw] = u + 1;
            }
            // ---- head partial AFTER publish (off-chain; w4 reads lag-2) ----
            // xor {2,4,16,32}: sum q2+quad dims, skip batch(1) and dup(8).
            float p = h * wl_u;
            p += __shfl_xor(p, 2);
            p += __shfl_xor(p, 4);
            p += __shfl_xor(p, 16);
            p += __shfl_xor(p, 32);
            if (lane < NBat)                   // lanes 0,1: bsel==lane
                headp[u & 3][lane][gw] = p;
        }
        // ---- tail-done: order the FINAL headp write (the race R26 hit) ----
        if (lane == 0) {
            asm volatile("" ::: "memory");
            *(volatile int*)&flg2[gw] = 1;
        }
        // ---- tail: out(Tt-2), out(Tt-1) after ALL headp(Tt-1) visible ----
        if (w == 4) {
            for (;;) {
                int a = ((const volatile int*)flg2)[0];
                int b = ((const volatile int*)flg2)[1];
                int c = ((const volatile int*)flg2)[2];
                int d = ((const volatile int*)flg2)[3];
                if ((a & b & c & d) != 0) break;
            }
            __builtin_amdgcn_sched_barrier(0);
            asm volatile("" ::: "memory");
            if (lane < NBat) {
                f32x4 v2 = *(const f32x4*)&headp[(Tt - 2) & 3][lane][0];
                outbuf[lane * Tt + (Tt - 2)] = blin + (v2[0] + v2[1]) + (v2[2] + v2[3]);
                f32x4 v1 = *(const f32x4*)&headp[(Tt - 1) & 3][lane][0];
                outbuf[lane * Tt + (Tt - 1)] = blin + (v1[0] + v1[1]) + (v1[2] + v1[3]);
            }
        }
    }
    __syncthreads();
    // ---- cooperative coalesced flush: LDS outbuf -> global out ----
    for (int i = tid; i < NBat * Tt; i += 512)
        st(out, (bb + (i >> 10)) * Tt + (i & 1023), outbuf[i], f32);
}

extern "C" void kernel_launch(void* const* d_in, const int* in_sizes, int n_in,
                              void* d_out, int out_size, void* d_ws, size_t ws_size,
                              hipStream_t stream)
{
    (void)in_sizes; (void)n_in; (void)out_size; (void)d_ws; (void)ws_size;
    lstm2_kernel<<<dim3(Bb / NBat), dim3(512), 0, stream>>>(
        d_in[0], d_in[1], d_in[2], d_in[3], d_in[4], d_in[5],
        d_in[6], d_in[7], d_in[8], d_in[9], d_in[10], d_out);
}

// Round 13
// 723.876 us; speedup vs baseline: 1.7708x; 1.7708x over previous
//
#include <hip/hip_runtime.h>
#include <hip/hip_bf16.h>

// LSTM2: B=1024, T=1024, H=64. R29 == R28 resubmitted (R12 bench was an
// infra failure: "MI355X container failed twice"; no kernel data).
// R28 = R23 (best, 718us) + the flg2 tail-done fix proven in R27. NO
// other changes.
// R27 post-mortem (1282us): 2 blocks/CU with NBat=2 DOUBLES total MFMA work
// (16x16 MFMA can't use <16 cols; batch replication x8 wastes 14/16) and
// the co-resident blocks contend -> occupancy up, time 1.8x worse. NBat=4
// at 1 block/CU is the per-CU work optimum for this shape.
// R27 also proved the tail race is real: R23 writes headp[u&3] AFTER
// publishing qf=u+1 (deliberate -- off the critical chain). In-loop lag-2
// reads are ordered by a LATER publish (same-wave DS in-order; depth-4
// slots can't collide under spread<=1), but the FINAL headp(Tt-1) write
// has no later publish -- tail poll qf>=Tt does NOT order it. R23 passed
// by timing luck. Fix (R27-verified): flg2[4] -- each Q wave's lane 0
// publishes flg2[gw]=1 AFTER its final headp write; w4's tail spins on
// all four flg2 before reading headp(Tt-2)/(Tt-1).
// R23 recap: decoupled P/Q flag pipelines; batch-replicated MFMA cols
// (B col n = batch n&3; lane (quad,m) owns cell (batch m&3, unit
// 16gw+4*(m>>2)+quad) in acc[m>>2]; 12-cndmask register mux -- no scr
// LDS roundtrip); Q publishes right after h2 write, head partial after
// publish (w4 reads headp at lag 2 from depth-4 buffer); pre-scaled
// activations; depth-1 P MFMAs; 2-deep Q chains; setprio around MFMA;
// ai-init hoisted above poll; HSTR=80; LDS outbuf + coalesced flush.
// Protocol (audited R19/R20): h1ring 4-deep, P<=3 ahead; flg[0..3]=pf,
// flg[4..7]=qf; lane-0 publish after the guarded ds_write (same-wave DS
// in-order). P(t): min(pf)>=t && min(qf)>=t-3. Q(u): min(pf)>=u+1 &&
// min(qf)>=u.
// Layouts (m89/m91/m120): A[m=lane&15][k=(lane>>4)*8+j],
// B[k=(lane>>4)*8+j][n=lane&15], C/D: row=(lane>>4)*4+reg, col=lane&15.

typedef _Float16 f16x8 __attribute__((ext_vector_type(8)));
typedef float    f32x4 __attribute__((ext_vector_type(4)));

namespace {
constexpr int Bb = 1024;
constexpr int Tt = 1024;
constexpr int NBat = 4;    // batches per block
constexpr int HSTR = 80;   // f16 stride per batch row of h (bank-tuned)
constexpr int XSTR = 1025; // f32 stride per batch row of x

// Pre-scaled activations: gate rows of W/b folded with -log2e (i,f,o) and
// -2log2e (g) at load, so no input multiply here.
__device__ __forceinline__ float sigm_pre(float a) {   // a = -1.4427*x
    return __builtin_amdgcn_rcpf(1.0f + __builtin_amdgcn_exp2f(a));
}
__device__ __forceinline__ float tanh_pre(float a) {   // a = -2.8854*x
    return fmaf(2.0f, __builtin_amdgcn_rcpf(1.0f + __builtin_amdgcn_exp2f(a)), -1.0f);
}
__device__ __forceinline__ float tanh_f(float x) {     // unscaled input (c-path)
    float e = __builtin_amdgcn_exp2f(-2.8853900817779268f * x);
    return fmaf(2.0f, __builtin_amdgcn_rcpf(1.0f + e), -1.0f);
}
// Dtype sniff (proven R2-R27).
__device__ __forceinline__ bool detect_f32(const void* w) {
    const unsigned short* p = (const unsigned short*)w;
    int sane = 0;
    for (int i = 0; i < 64; ++i) {
        int e = (p[2 * i] >> 7) & 0xFF;
        if (e >= 107 && e <= 129) ++sane;
    }
    return sane < 32;
}
__device__ __forceinline__ float ld(const void* p, int i, bool f32) {
    return f32 ? ((const float*)p)[i]
               : __bfloat162float(((const __hip_bfloat16*)p)[i]);
}
__device__ __forceinline__ void st(void* p, int i, float v, bool f32) {
    if (f32) ((float*)p)[i] = v;
    else     ((__hip_bfloat16*)p)[i] = __float2bfloat16(v);
}
// Lane-parallel spin: lane i watches flg[i&7]; P-flags (idx<4) against tp,
// Q-flags against tq. ONE broadcast ds_read_b32 per spin, __all ballot.
__device__ __forceinline__ void poll_flags(const int* f, int tp, int tq, int lane) {
    const int idx = lane & 7;
    const int thr = (idx < 4) ? tp : tq;
    for (;;) {
        int v = ((const volatile int*)f)[idx];
        if (__all(v >= thr)) break;
    }
    __builtin_amdgcn_sched_barrier(0);
    asm volatile("" ::: "memory");
}
} // namespace

__global__ __launch_bounds__(512, 1) void lstm2_kernel(
    const void* __restrict__ x,      // [B, T]
    const void* __restrict__ w_ih1,  // [256, 1]
    const void* __restrict__ w_hh1,  // [256, 64]
    const void* __restrict__ b_ih1,  // [256]
    const void* __restrict__ b_hh1,  // [256]
    const void* __restrict__ w_ih2,  // [256, 64]
    const void* __restrict__ w_hh2,  // [256, 64]
    const void* __restrict__ b_ih2,  // [256]
    const void* __restrict__ b_hh2,  // [256]
    const void* __restrict__ w_lin,  // [1, 64]
    const void* __restrict__ b_lin,  // [1]
    void* __restrict__ out)          // [B, T]
{
    const int tid  = threadIdx.x;
    const int lane = tid & 63;
    const int w    = tid >> 6;       // wave 0..7
    const int gw   = w & 3;          // group-local wave -> unit group 16gw..
    const bool isP = w < 4;          // P: L1 recurrence; Q: L2 pipeline
    const int m    = lane & 15;      // MFMA col
    const int quad = lane >> 4;
    const int bb   = blockIdx.x * NBat;

    const bool f32 = detect_f32(w_hh1);

    __shared__ float                  xs[NBat * XSTR];
    __shared__ __align__(16) _Float16 h1ring[4][NBat * HSTR]; // 4-deep ring
    __shared__ __align__(16) _Float16 h2buf[2][NBat * HSTR];  // parity (Q)
    __shared__ __align__(16) float    headp[4][NBat][4];      // [u&3][b][gw]
    __shared__ float                  outbuf[NBat * Tt];      // staged outputs
    __shared__ int                    flg[8];                 // 0..3 pf, 4..7 qf
    __shared__ int                    flg2[4];                // tail-done per Q wave

    // ---- stage x + zero h buffers ----
    for (int i = tid; i < NBat * 1024; i += 512)
        xs[(i >> 10) * XSTR + (i & 1023)] = ld(x, (bb + (i >> 10)) * Tt + (i & 1023), f32);
    for (int i = tid; i < NBat * HSTR; i += 512) {
        h1ring[0][i] = (_Float16)0; h1ring[1][i] = (_Float16)0;
        h1ring[2][i] = (_Float16)0; h1ring[3][i] = (_Float16)0;
        h2buf[0][i] = (_Float16)0;  h2buf[1][i] = (_Float16)0;
    }
    if (tid < 8) flg[tid] = 0;
    if (tid < 4) flg2[tid] = 0;

    // ---- A-fragments, gate-interleaved rows (R13), activation-scale folded ----
    // tile row (lane&15) = 4*u_loc + g -> mem row 64*g + 16*gw + 4q + u_loc
    const int arow = lane & 15;
    const int g_ld = arow & 3;
    const int u_ld = arow >> 2;
    const float scA = (g_ld == 2) ? -2.8853900817779268f : -1.4426950408889634f;
    f16x8 wfA[4][2], wfB[4][2];   // P: wfA=W1 (wfB zero); Q: wfA=W2, wfB=W3
    {
        const void* MA = isP ? w_hh1 : w_ih2;
#pragma unroll
        for (int q = 0; q < 4; ++q) {
            const int row = 64 * g_ld + 16 * gw + 4 * q + u_ld;
#pragma unroll
            for (int s = 0; s < 2; ++s) {
                const int base = row * 64 + 32 * s + quad * 8;
                if (f32) {
                    const float* A = (const float*)MA;
                    const float* B = (const float*)w_hh2;
#pragma unroll
                    for (int j = 0; j < 8; ++j) {
                        wfA[q][s][j] = (_Float16)(scA * A[base + j]);
                        wfB[q][s][j] = isP ? (_Float16)0.0f
                                           : (_Float16)(scA * B[base + j]);
                    }
                } else {
                    const __hip_bfloat16* A = (const __hip_bfloat16*)MA;
                    const __hip_bfloat16* B = (const __hip_bfloat16*)w_hh2;
#pragma unroll
                    for (int j = 0; j < 8; ++j) {
                        wfA[q][s][j] = (_Float16)(scA * __bfloat162float(A[base + j]));
                        wfB[q][s][j] = isP ? (_Float16)0.0f
                                           : (_Float16)(scA * __bfloat162float(B[base + j]));
                    }
                }
            }
        }
    }
    // bias / wx per (tile q, gate r): D row r of tile q = gate r, unit 16gw+4q+quad
    f32x4 bv[4], wxv[4];
#pragma unroll
    for (int q = 0; q < 4; ++q)
#pragma unroll
        for (int r = 0; r < 4; ++r) {
            const int row = 64 * r + 16 * gw + 4 * q + quad;
            const float sg = (r == 2) ? -2.8853900817779268f : -1.4426950408889634f;
            bv[q][r] = sg * (isP ? (ld(b_ih1, row, f32) + ld(b_hh1, row, f32))
                                 : (ld(b_ih2, row, f32) + ld(b_hh2, row, f32)));
            wxv[q][r] = isP ? sg * ld(w_ih1, row, f32) : 0.0f;
        }
    // cell ownership (batch-replicated cols): lane (quad,m) owns
    // (batch m&3, unit 16gw + 4*(m>>2) + quad), gates in acc[m>>2].
    const int q2   = m >> 2;
    const int bsel = m & 3;
    const int hidx = bsel * HSTR + 16 * gw + 4 * q2 + quad;  // own h slot
    const bool s1 = (q2 & 1) != 0, s2 = (q2 & 2) != 0;
    const float wl_u = ld(w_lin, 16 * gw + 4 * q2 + quad, f32);
    const float blin = ld(b_lin, 0, f32);
    float cst = 0.0f;                 // c-state of the owned cell
    __syncthreads();   // xs + zeroed bufs + flags visible

    if (isP) {
        // ================= P: L1 recurrence, self-paced =================
#pragma unroll 4
        for (int t = 0; t < Tt; ++t) {
            // acc-init before poll: reads only static xs/regs
            const float xt = xs[bsel * XSTR + t];
            f32x4 ai[4];
#pragma unroll
            for (int q = 0; q < 4; ++q)
#pragma unroll
                for (int r = 0; r < 4; ++r)
                    ai[q][r] = fmaf(xt, wxv[q][r], bv[q][r]);
            poll_flags(flg, t, t - 3, lane);   // group sync + ring-not-full
            f32x4 acc[4];
            if (t > 0) {
                const _Float16* hp = h1ring[(t - 1) & 3] + bsel * HSTR;
                const f16x8 pa0 = *(const f16x8*)(hp + quad * 8);
                const f16x8 pa1 = *(const f16x8*)(hp + 32 + quad * 8);
                __builtin_amdgcn_s_setprio(1);
#pragma unroll
                for (int q = 0; q < 4; ++q) {   // depth-1: independent k-halves
                    f32x4 p0 = __builtin_amdgcn_mfma_f32_16x16x32_f16(wfA[q][0], pa0, ai[q], 0, 0, 0);
                    f32x4 p1 = __builtin_amdgcn_mfma_f32_16x16x32_f16(wfA[q][1], pa1, f32x4{0,0,0,0}, 0, 0, 0);
                    acc[q] = p0 + p1;
                }
                __builtin_amdgcn_s_setprio(0);
            } else {
#pragma unroll
                for (int q = 0; q < 4; ++q) acc[q] = ai[q];
            }
            // ---- register mux: g = acc[q2] (12 cndmasks, no LDS) ----
            f32x4 g;
#pragma unroll
            for (int r = 0; r < 4; ++r) {
                float lo = s1 ? acc[1][r] : acc[0][r];
                float hi = s1 ? acc[3][r] : acc[2][r];
                g[r] = s2 ? hi : lo;
            }
            // ---- cell (1 per lane) ----
            float ig = sigm_pre(g[0]), fg = sigm_pre(g[1]);
            float gg = tanh_pre(g[2]), og = sigm_pre(g[3]);
            cst = fmaf(fg, cst, ig * gg);
            h1ring[t & 3][hidx] = (_Float16)(og * tanh_f(cst));
            if (lane == 0) {          // publish: DS in-order, no waitcnt
                asm volatile("" ::: "memory");
                *(volatile int*)&flg[gw] = t + 1;
            }
        }
    } else {
        // ================= Q: L2 pipeline, self-paced =================
#pragma unroll 4
        for (int u = 0; u < Tt; ++u) {
            poll_flags(flg, u + 1, u, lane);   // h1(u) ready + own group done u-1
            // ---- finalize out(u-2) -> LDS outbuf (lag 2, off-chain) ----
            if (u > 1 && w == 4 && lane < NBat) {
                f32x4 v = *(const f32x4*)&headp[(u - 2) & 3][lane][0];
                outbuf[lane * Tt + (u - 2)] = blin + (v[0] + v[1]) + (v[2] + v[3]);
            }
            // ---- a2(u) = W2.h1(u) + W3.h2(u-1) + b2 (pre-scaled) ----
            const _Float16* h1p = h1ring[u & 3] + bsel * HSTR;
            const _Float16* h2p = h2buf[(u + 1) & 1] + bsel * HSTR;  // (u-1) parity
            const f16x8 pa0 = *(const f16x8*)(h1p + quad * 8);
            const f16x8 pa1 = *(const f16x8*)(h1p + 32 + quad * 8);
            const f16x8 pb0 = *(const f16x8*)(h2p + quad * 8);
            const f16x8 pb1 = *(const f16x8*)(h2p + 32 + quad * 8);
            f32x4 acc[4];
            __builtin_amdgcn_s_setprio(1);
#pragma unroll
            for (int q = 0; q < 4; ++q) {   // two independent 2-deep chains
                f32x4 p2 = __builtin_amdgcn_mfma_f32_16x16x32_f16(wfA[q][0], pa0, bv[q], 0, 0, 0);
                p2 = __builtin_amdgcn_mfma_f32_16x16x32_f16(wfA[q][1], pa1, p2, 0, 0, 0);
                f32x4 p3 = __builtin_amdgcn_mfma_f32_16x16x32_f16(wfB[q][0], pb0, f32x4{0,0,0,0}, 0, 0, 0);
                p3 = __builtin_amdgcn_mfma_f32_16x16x32_f16(wfB[q][1], pb1, p3, 0, 0, 0);
                acc[q] = p2 + p3;
            }
            __builtin_amdgcn_s_setprio(0);
            // ---- register mux + cell ----
            f32x4 g;
#pragma unroll
            for (int r = 0; r < 4; ++r) {
                float lo = s1 ? acc[1][r] : acc[0][r];
                float hi = s1 ? acc[3][r] : acc[2][r];
                g[r] = s2 ? hi : lo;
            }
            float ig = sigm_pre(g[0]), fg = sigm_pre(g[1]);
            float gg = tanh_pre(g[2]), og = sigm_pre(g[3]);
            cst = fmaf(fg, cst, ig * gg);
            float h = og * tanh_f(cst);
            h2buf[u & 1][hidx] = (_Float16)h;
            if (lane == 0) {          // publish right after h2 write
                asm volatile("" ::: "memory");
                *(volatile int*)&flg[4 + gw] = u + 1;
            }
            // ---- head partial AFTER publish (off-chain; w4 reads lag-2) ----
            float p = h * wl_u;                // sum over own wave's 16 units
            p += __shfl_xor(p, 4);
            p += __shfl_xor(p, 8);
            p += __shfl_xor(p, 16);
            p += __shfl_xor(p, 32);
            if (lane < NBat)                   // lane==bsel, full slice sum
                headp[u & 3][lane][gw] = p;
        }
        // ---- tail-done: order the FINAL headp write (race fixed in R27) ----
        if (lane == 0) {
            asm volatile("" ::: "memory");
            *(volatile int*)&flg2[gw] = 1;
        }
        // ---- tail: out(Tt-2), out(Tt-1) after ALL headp(Tt-1) visible ----
        if (w == 4) {
            for (;;) {
                int a = ((const volatile int*)flg2)[0];
                int b = ((const volatile int*)flg2)[1];
                int c = ((const volatile int*)flg2)[2];
                int d = ((const volatile int*)flg2)[3];
                if ((a & b & c & d) != 0) break;
            }
            __builtin_amdgcn_sched_barrier(0);
            asm volatile("" ::: "memory");
            if (lane < NBat) {
                f32x4 v2 = *(const f32x4*)&headp[(Tt - 2) & 3][lane][0];
                outbuf[lane * Tt + (Tt - 2)] = blin + (v2[0] + v2[1]) + (v2[2] + v2[3]);
                f32x4 v1 = *(const f32x4*)&headp[(Tt - 1) & 3][lane][0];
                outbuf[lane * Tt + (Tt - 1)] = blin + (v1[0] + v1[1]) + (v1[2] + v1[3]);
            }
        }
    }
    __syncthreads();
    // ---- cooperative coalesced flush: LDS outbuf -> global out ----
    for (int i = tid; i < NBat * Tt; i += 512)
        st(out, (bb + (i >> 10)) * Tt + (i & 1023), outbuf[i], f32);
}

extern "C" void kernel_launch(void* const* d_in, const int* in_sizes, int n_in,
                              void* d_out, int out_size, void* d_ws, size_t ws_size,
                              hipStream_t stream)
{
    (void)in_sizes; (void)n_in; (void)out_size; (void)d_ws; (void)ws_size;
    lstm2_kernel<<<dim3(Bb / NBat), dim3(512), 0, stream>>>(
        d_in[0], d_in[1], d_in[2], d_in[3], d_in[4], d_in[5],
        d_in[6], d_in[7], d_in[8], d_in[9], d_in[10], d_out);
}